// Round 13
// baseline (451.702 us; speedup 1.0000x reference)
//
#include <hip/hip_runtime.h>

// SoftmaxMatcher on MI355X — round 13.
// Ring-4 x 16KB HALF-unit staging (64px x 128ch):
//  * LDS 64KB -> 2 blocks/CU co-resident (VGPR ~110 <= 128) => cross-block
//    overlap of WAITV/SBAR stalls (m114), which R12's 96KB ring killed.
//  * prefetch depth 4 half-phases; stage issued at END of phase into the
//    buffer just freed; FIFO-exact waits (tables below) keep needed loads
//    always older than pending osm stores -> stores never forced.
//  * s_setprio(1) around MFMA clusters (T5) — pays now that a co-resident
//    second block provides scheduler role diversity.
//  * all 8 waves compute the same 64-px half: wq=w>>2 (32px), wn=w&3 (32kp),
//    acc[hb][mf][nf].

typedef short  v8s __attribute__((ext_vector_type(8)));
typedef unsigned short v8u __attribute__((ext_vector_type(8)));
typedef float  v4f __attribute__((ext_vector_type(4)));

#define EXP2_SCALE 144.269504088896f   // 1/(0.01*ln2)
#define WAITV(N) asm volatile("s_waitcnt vmcnt(" #N ")" ::: "memory")
#define SBAR()   __builtin_amdgcn_s_barrier()
#define SCHED()  __builtin_amdgcn_sched_barrier(0)
#define PRIO(N)  __builtin_amdgcn_s_setprio(N)

// ---- workspace layout (bytes) ----
static const size_t O_AHI  = 0;                        // ushort[2048*128]
static const size_t O_ALO  = O_AHI  + 262144ull*2;
static const size_t O_SRCN = O_ALO  + 262144ull*2;     // float[2048*128]
static const size_t O_BHI  = O_SRCN + 262144ull*4;     // ushort[262144*128] 64MB
static const size_t O_BLO  = O_BHI  + 33554432ull*2;   // 64MB
static const size_t O_PART = O_BLO  + 33554432ull*2;   // float4[2048*512]   16MB
static const size_t O_ROWS = O_PART + 2048ull*512*16;  // float4[2048]

static __device__ inline unsigned short f2bf(float x) {
    unsigned u = __float_as_uint(x);
    u = u + 0x7FFFu + ((u >> 16) & 1u);   // RNE
    return (unsigned short)(u >> 16);
}
static __device__ inline float bf2f(unsigned short h) {
    return __uint_as_float(((unsigned)h) << 16);
}

__device__ __forceinline__ void gl_lds16(const void* g, void* l) {
    auto gp = (const __attribute__((address_space(1))) unsigned int*)(uintptr_t)g;
    auto lp = (__attribute__((address_space(3))) unsigned int*)(uintptr_t)l;
    __builtin_amdgcn_global_load_lds(gp, lp, 16, 0, 0);
}

// ---------------- prep: normalize src keypoint descs, bf16 hi/lo, [row][k] ----
__global__ void __launch_bounds__(256) k_prep_src(const float* __restrict__ kd,
                                                  float* __restrict__ srcN,
                                                  unsigned short* __restrict__ Ahi,
                                                  unsigned short* __restrict__ Alo) {
    int gw = blockIdx.x * 4 + (threadIdx.x >> 6);  // 0..2047 = b*512+n
    int l  = threadIdx.x & 63;
    int b  = gw >> 9, n = gw & 511;
    const float* base = kd + (size_t)(2 * b) * 128 * 512;
    float x0 = base[l * 512 + n];
    float x1 = base[(l + 64) * 512 + n];
    float ss = x0 * x0 + x1 * x1;
#pragma unroll
    for (int m = 1; m < 64; m <<= 1) ss += __shfl_xor(ss, m, 64);
    float inv = 1.0f / fmaxf(sqrtf(ss), 1e-12f);
    float xn0 = x0 * inv, xn1 = x1 * inv;
    int ob = gw * 128;
    srcN[ob + l] = xn0;  srcN[ob + l + 64] = xn1;
    unsigned short h0 = f2bf(xn0), h1 = f2bf(xn1);
    Ahi[ob + l] = h0;        Ahi[ob + l + 64] = h1;
    Alo[ob + l] = f2bf(xn0 - bf2f(h0));
    Alo[ob + l + 64] = f2bf(xn1 - bf2f(h1));
}

// ---------------- prep: normalize tgt dense descs -> [m][k] hi/lo -------------
__global__ void __launch_bounds__(256) k_prep_tgt(const float* __restrict__ dd,
                                                  unsigned short* __restrict__ Bhi,
                                                  unsigned short* __restrict__ Blo) {
    int t = blockIdx.x * 128 + (threadIdx.x >> 1);   // 0..262143 = b*65536+p
    int h = threadIdx.x & 1;
    int b = t >> 16;
    int p = t & 65535;
    const float* src = dd + (size_t)(2 * b + 1) * 128 * 65536 + (size_t)(h * 64) * 65536 + p;
    float v[64];
    float ss = 0.f;
#pragma unroll
    for (int c = 0; c < 64; ++c) { float x = src[(size_t)c * 65536]; v[c] = x; ss += x * x; }
    ss += __shfl_xor(ss, 1, 64);
    float inv = 1.0f / fmaxf(sqrtf(ss), 1e-12f);
    size_t ob = (size_t)t * 128 + h * 64;
#pragma unroll
    for (int c8 = 0; c8 < 8; ++c8) {
        v8u h8, l8;
#pragma unroll
        for (int j = 0; j < 8; ++j) {
            float xn = v[c8 * 8 + j] * inv;
            unsigned short hh = f2bf(xn);
            h8[j] = hh;
            l8[j] = f2bf(xn - bf2f(hh));
        }
        *(v8u*)(Bhi + ob + c8 * 8) = h8;
        *(v8u*)(Blo + ob + c8 * 8) = l8;
    }
}

// ---------------- fused GEMM: ring-4 half-unit staged, 16 tiles/block --------
// grid (32 mtg, 4 ny, 4 b) = 512 blocks, 512 thr = 8 waves, 2 blocks/CU.
// wave: wq = w>>2 (32-px sub-strip), wn = w&3 (32-kp strip).
// acc[hb 2][mf 2][nf 2]: px m = hb*64+wq*32+mf*16+l16*4+r; kp n = wn*32+nf*16+l15.
// MODE 0: 2-term (Bhi only); per-(row,mt,wq) partials {S, M} -> part.
// MODE 1: 3-term; p = e*invS -> osm (direct v4f stores); sample tail.
template <int MODE>
__global__ void __launch_bounds__(512, 2) k_gemm(const unsigned short* __restrict__ Ahi,
                                                 const unsigned short* __restrict__ Alo,
                                                 const unsigned short* __restrict__ Bhi,
                                                 const unsigned short* __restrict__ Blo,
                                                 const float4* __restrict__ rows,
                                                 float* __restrict__ part,
                                                 float* __restrict__ out,
                                                 const float* __restrict__ ksc,
                                                 const float* __restrict__ sd,
                                                 const float* __restrict__ dd,
                                                 const float* __restrict__ srcN) {
    __shared__ v4f bstage4[4096];          // 64 KB: 4 x 16KB half-unit ring
    char* bstage = (char*)bstage4;

    const int tid = threadIdx.x;
    const int l = tid & 63, w = tid >> 6;
    const int wq = w >> 2, wn = w & 3;
    const int l15 = l & 15, l16 = l >> 4;
    const int mtg = blockIdx.x, ny = blockIdx.y, b = blockIdx.z;
    const int mt0 = mtg * 16;
    float* osm = out + 6144;

    // ---- A fragments in VGPRs: [nf 2][ksl 4], hi + lo (64 VGPR) ----
    v8s ahi[2][4], alo[2][4];
    {
        const size_t ar = ((size_t)(b * 512 + ny * 128 + wn * 32 + l15)) * 128 + l16 * 8;
#pragma unroll
        for (int nf = 0; nf < 2; ++nf)
#pragma unroll
            for (int ksl = 0; ksl < 4; ++ksl) {
                ahi[nf][ksl] = *(const v8s*)(Ahi + ar + nf * 2048 + ksl * 32);
                alo[nf][ksl] = *(const v8s*)(Alo + ar + nf * 2048 + ksl * 32);
            }
    }
    float invs[2];
    if (MODE == 1) {
#pragma unroll
        for (int nf = 0; nf < 2; ++nf)
            invs[nf] = rows[b * 512 + ny * 128 + wn * 32 + nf * 16 + l15].x;
    }
    WAITV(0);                               // A regs ready; clean per-wave FIFO

    const size_t pxbase = ((size_t)b * 65536 + (size_t)mt0 * 128) * 128;

    // Stage one 16KB half-unit (64 px x 128 ch): 2 gl_lds16 per thread.
#define STAGEH(SRC, eoff, bufidx)                                                   \
    {                                                                               \
        const unsigned short* src_ = (SRC) + pxbase + (eoff);                       \
        char* dst_ = bstage + (bufidx) * 16384;                                     \
        _Pragma("unroll")                                                           \
        for (int i = 0; i < 2; ++i) {                                               \
            int sl = tid + i * 512;                                                 \
            int rl = sl >> 4, gg = sl & 15;                                         \
            gl_lds16(src_ + rl * 128 + ((gg ^ (rl & 15)) << 3), dst_ + (sl << 4));  \
        }                                                                           \
    }
    // pxf read: local row rloc (0..63), slot (ksl*4+l16)^(rloc&15)
#define PXF(bufbase, mf_, ksl_)                                                     \
    (*(const v8s*)((bufbase) + (wq * 32 + (mf_) * 16 + l15) * 256 +                 \
                   ((((ksl_) * 4 + l16) ^ ((wq * 32 + (mf_) * 16 + l15) & 15)) << 4)))

    v4f acc[2][2][2];

    if (MODE == 0) {
        // halves H_h (h=0..31): tile t=h>>1, hb=h&1; elem off = h*8192.
        // Stage H_{h+4} at END of phase h (h<28) into buf h%4 (just freed).
        // Per-wave FIFO (stage=2 items, tile-end stores=2 instrs at odd h):
        //   h0,1: 6 | h2,3: 8 | h4..28: 10 | h29: 8 | h30: 6 | h31: 4
        STAGEH(Bhi, 0, 0); STAGEH(Bhi, 8192, 1);
        STAGEH(Bhi, 16384, 2); STAGEH(Bhi, 24576, 3);
#pragma unroll 1
        for (int h = 0; h < 32; ++h) {
            if (h <= 1) WAITV(6);
            else if (h <= 3) WAITV(8);
            else if (h <= 28) WAITV(10);
            else if (h == 29) WAITV(8);
            else if (h == 30) WAITV(6);
            else WAITV(4);
            SBAR(); SCHED();
            const int hb = h & 1;
            if (hb == 0) {
#pragma unroll
                for (int q = 0; q < 2; ++q)
#pragma unroll
                    for (int mf = 0; mf < 2; ++mf)
#pragma unroll
                        for (int nf = 0; nf < 2; ++nf) { v4f z = {0.f,0.f,0.f,0.f}; acc[q][mf][nf] = z; }
            }
            const char* bb = bstage + (h & 3) * 16384;
            PRIO(1);
#pragma unroll
            for (int ksl = 0; ksl < 4; ++ksl) {
                v8s pxf[2];
#pragma unroll
                for (int mf = 0; mf < 2; ++mf) pxf[mf] = PXF(bb, mf, ksl);
#pragma unroll
                for (int mf = 0; mf < 2; ++mf)
#pragma unroll
                    for (int nf = 0; nf < 2; ++nf) {
                        acc[hb][mf][nf] = __builtin_amdgcn_mfma_f32_16x16x32_bf16(pxf[mf], ahi[nf][ksl], acc[hb][mf][nf], 0, 0, 0);
                        acc[hb][mf][nf] = __builtin_amdgcn_mfma_f32_16x16x32_bf16(pxf[mf], alo[nf][ksl], acc[hb][mf][nf], 0, 0, 0);
                    }
            }
            PRIO(0);
            SCHED(); SBAR();
            if (h < 28) STAGEH(Bhi, (size_t)(h + 4) * 8192, h & 3);
            if (hb == 1) {
                // tile t = h>>1 epilogue: {S, M} partials, 2 stores (l<16)
                int mt = h >> 1;
                float sS[2] = {0.f, 0.f}, sM[2] = {0.f, 0.f};
#pragma unroll
                for (int q = 0; q < 2; ++q)
#pragma unroll
                    for (int mf = 0; mf < 2; ++mf) {
                        int mloc = q * 64 + wq * 32 + mf * 16 + l16 * 4;
#pragma unroll
                        for (int nf = 0; nf < 2; ++nf)
#pragma unroll
                            for (int r = 0; r < 4; ++r) {
                                float e = __builtin_amdgcn_exp2f(fmaf(acc[q][mf][nf][r], EXP2_SCALE, -EXP2_SCALE));
                                sS[nf] += e;
                                sM[nf] = fmaf(e, (float)(mloc + r), sM[nf]);
                            }
                    }
#pragma unroll
                for (int nf = 0; nf < 2; ++nf) {
                    sS[nf] += __shfl_xor(sS[nf], 16, 64); sS[nf] += __shfl_xor(sS[nf], 32, 64);
                    sM[nf] += __shfl_xor(sM[nf], 16, 64); sM[nf] += __shfl_xor(sM[nf], 32, 64);
                }
                if (l < 16) {
#pragma unroll
                    for (int nf = 0; nf < 2; ++nf) {
                        int row = b * 512 + ny * 128 + wn * 32 + nf * 16 + l15;
                        *(float2*)(part + (((size_t)row * 512 + (mt0 + mt)) * 2 + wq) * 2)
                            = make_float2(sS[nf], sM[nf]);
                    }
                }
            }
        }
    } else {
        // phases p=0..63: tile t=p>>2, sub=p&3: {Bhi h0, Bhi h1, Blo h0, Blo h1}
        // elem off(p) = (p>>2)*16384 + (p&1)*8192. Stage P_{p+4} at END (p<60).
        // FIFO: p0..3: 6 | p4..60: 14 | p61: 12 | p62: 10 | p63: 8
        STAGEH(Bhi, 0, 0); STAGEH(Bhi, 8192, 1);
        STAGEH(Blo, 0, 2); STAGEH(Blo, 8192, 3);
#pragma unroll 1
        for (int p = 0; p < 64; ++p) {
            if (p <= 3) WAITV(6);
            else if (p <= 60) WAITV(14);
            else if (p == 61) WAITV(12);
            else if (p == 62) WAITV(10);
            else WAITV(8);
            SBAR(); SCHED();
            const int sub = p & 3, hb = sub & 1;
            if (sub == 0) {
#pragma unroll
                for (int q = 0; q < 2; ++q)
#pragma unroll
                    for (int mf = 0; mf < 2; ++mf)
#pragma unroll
                        for (int nf = 0; nf < 2; ++nf) { v4f z = {0.f,0.f,0.f,0.f}; acc[q][mf][nf] = z; }
            }
            const char* bb = bstage + (p & 3) * 16384;
            PRIO(1);
#pragma unroll
            for (int ksl = 0; ksl < 4; ++ksl) {
                v8s pxf[2];
#pragma unroll
                for (int mf = 0; mf < 2; ++mf) pxf[mf] = PXF(bb, mf, ksl);
#pragma unroll
                for (int mf = 0; mf < 2; ++mf)
#pragma unroll
                    for (int nf = 0; nf < 2; ++nf) {
                        acc[hb][mf][nf] = __builtin_amdgcn_mfma_f32_16x16x32_bf16(pxf[mf], ahi[nf][ksl], acc[hb][mf][nf], 0, 0, 0);
                        if (sub < 2)
                            acc[hb][mf][nf] = __builtin_amdgcn_mfma_f32_16x16x32_bf16(pxf[mf], alo[nf][ksl], acc[hb][mf][nf], 0, 0, 0);
                    }
            }
            PRIO(0);
            SCHED(); SBAR();
            if (p < 60) {
                const int pn = p + 4;
                const size_t eoff = (size_t)(pn >> 2) * 16384 + (size_t)(pn & 1) * 8192;
                if ((pn & 2) == 0) STAGEH(Bhi, eoff, pn & 3)
                else               STAGEH(Blo, eoff, pn & 3)
            }
            if (sub == 3) {
                // tile epilogue: direct p stores (8 v4f per thread, along m)
                int mt = p >> 2;
                size_t mg0 = (size_t)(mt0 + mt) * 128 + wq * 32 + l16 * 4;
#pragma unroll
                for (int q = 0; q < 2; ++q)
#pragma unroll
                    for (int mf = 0; mf < 2; ++mf)
#pragma unroll
                        for (int nf = 0; nf < 2; ++nf) {
                            v4f pv;
#pragma unroll
                            for (int r = 0; r < 4; ++r)
                                pv[r] = __builtin_amdgcn_exp2f(fmaf(acc[q][mf][nf][r], EXP2_SCALE, -EXP2_SCALE)) * invs[nf];
                            size_t ng = (size_t)(b * 512 + ny * 128 + wn * 32 + nf * 16 + l15);
                            __builtin_nontemporal_store(pv, (v4f*)(osm + ng * 65536 + mg0 + q * 64 + mf * 16));
                        }
            }
        }

        // ---- sample tail: 1 row per wave for waves 0..3 (512 blocks x 4) ----
        if (w < 4) {
            const int bidx = mtg + 32 * ny + 128 * b;     // 0..511
            const int r = bidx * 4 + w;                   // 0..2047
            const int rb = r >> 9;
            float4 rs = rows[r];
            float u = rs.y, v = rs.z;
            float un = 2.0f * u / 255.0f - 1.0f;
            float vn = 2.0f * v / 255.0f - 1.0f;
            float x = ((un + 1.0f) * 256.0f - 1.0f) * 0.5f;
            float y = ((vn + 1.0f) * 256.0f - 1.0f) * 0.5f;
            float x0f = floorf(x), y0f = floorf(y);
            int x0 = (int)x0f, y0 = (int)y0f;
            int x1 = x0 + 1, y1 = y0 + 1;
            float wx1 = x - x0f, wy1 = y - y0f;
            float wx0 = 1.0f - wx1, wy0 = 1.0f - wy1;
            float m00 = ((x0 >= 0) & (x0 <= 255) & (y0 >= 0) & (y0 <= 255)) ? 1.f : 0.f;
            float m10 = ((x1 >= 0) & (x1 <= 255) & (y0 >= 0) & (y0 <= 255)) ? 1.f : 0.f;
            float m01 = ((x0 >= 0) & (x0 <= 255) & (y1 >= 0) & (y1 <= 255)) ? 1.f : 0.f;
            float m11 = ((x1 >= 0) & (x1 <= 255) & (y1 >= 0) & (y1 <= 255)) ? 1.f : 0.f;
            int cx0 = min(max(x0, 0), 255), cx1 = min(max(x1, 0), 255);
            int cy0 = min(max(y0, 0), 255), cy1 = min(max(y1, 0), 255);
            int i00 = cy0 * 256 + cx0, i10 = cy0 * 256 + cx1;
            int i01 = cy1 * 256 + cx0, i11 = cy1 * 256 + cx1;
            float w00 = wx0 * wy0 * m00, w10 = wx1 * wy0 * m10;
            float w01 = wx0 * wy1 * m01, w11 = wx1 * wy1 * m11;

            const float* sdb = sd + (size_t)(2 * rb + 1) * 65536;
            float ps = w00 * sdb[i00] + w10 * sdb[i10] + w01 * sdb[i01] + w11 * sdb[i11];

            const float* ddb = dd + (size_t)(2 * rb + 1) * 128 * 65536;
            float dot = 0.f;
#pragma unroll
            for (int h2 = 0; h2 < 2; ++h2) {
                int c = l + h2 * 64;
                const float* dc = ddb + (size_t)c * 65536;
                float pd = w00 * dc[i00] + w10 * dc[i10] + w01 * dc[i01] + w11 * dc[i11];
                dot += srcN[r * 128 + c] * pd;
            }
#pragma unroll
            for (int m = 1; m < 64; m <<= 1) dot += __shfl_xor(dot, m, 64);
            if (l == 0) {
                float dms = dot / 128.0f;
                float sscore = ksc[(2 * rb) * 512 + (r & 511)];
                out[4096 + r] = 0.5f * (dms + 1.0f) * sscore * ps;
            }
        }
    }
#undef STAGEH
#undef PXF
}

// ---------------- reduce partials -> rowstats{invS,u,v}; write pseudo_coords ----
// part: [row 2048][mt 512][wq 2][{S,M}]  (float4 per (row,mt))
__global__ void __launch_bounds__(256) k_reduce(const float4* __restrict__ part,
                                                float4* __restrict__ rows,
                                                float* __restrict__ out) {
    int r = blockIdx.x * 4 + (threadIdx.x >> 6);  // 0..2047
    int l = threadIdx.x & 63;
    float S = 0.f, Su = 0.f, Sv = 0.f;
#pragma unroll
    for (int i = 0; i < 8; ++i) {
        int mt = l + i * 64;
        float4 pp = part[(size_t)r * 512 + mt];
        float Sp = pp.x + pp.z;       // wq0.S + wq1.S
        float Mp = pp.y + pp.w;       // M partials already carry local px index
        S += Sp;
        Su += (float)((mt & 1) * 128) * Sp + Mp;
        Sv += (float)(mt >> 1) * Sp;
    }
#pragma unroll
    for (int m = 1; m < 64; m <<= 1) {
        S += __shfl_xor(S, m, 64);
        Su += __shfl_xor(Su, m, 64);
        Sv += __shfl_xor(Sv, m, 64);
    }
    if (l == 0) {
        float invS = 1.0f / S;
        float u = Su * invS, v = Sv * invS;
        rows[r] = make_float4(invS, u, v, 0.f);
        out[r * 2] = u;
        out[r * 2 + 1] = v;
    }
}

extern "C" void kernel_launch(void* const* d_in, const int* in_sizes, int n_in,
                              void* d_out, int out_size, void* d_ws, size_t ws_size,
                              hipStream_t stream) {
    const float* ksc = (const float*)d_in[0];  // (8,1,512)
    const float* kd  = (const float*)d_in[1];  // (8,128,512)
    const float* sd  = (const float*)d_in[2];  // (8,1,256,256)
    const float* dd  = (const float*)d_in[3];  // (8,128,256,256)
    float* out = (float*)d_out;                // coords(4096) | mw(2048) | sm(134217728)
    char* ws = (char*)d_ws;

    unsigned short* Ahi  = (unsigned short*)(ws + O_AHI);
    unsigned short* Alo  = (unsigned short*)(ws + O_ALO);
    float*          srcN = (float*)(ws + O_SRCN);
    unsigned short* Bhi  = (unsigned short*)(ws + O_BHI);
    unsigned short* Blo  = (unsigned short*)(ws + O_BLO);
    float*          part = (float*)(ws + O_PART);
    float4*         rows = (float4*)(ws + O_ROWS);

    k_prep_src<<<512, 256, 0, stream>>>(kd, srcN, Ahi, Alo);
    k_prep_tgt<<<2048, 256, 0, stream>>>(dd, Bhi, Blo);
    k_gemm<0><<<dim3(32, 4, 4), 512, 0, stream>>>(Ahi, Alo, Bhi, Blo, rows, part, out, ksc, sd, dd, srcN);
    k_reduce<<<512, 256, 0, stream>>>((const float4*)part, rows, out);
    k_gemm<1><<<dim3(32, 4, 4), 512, 0, stream>>>(Ahi, Alo, Bhi, Blo, rows, part, out, ksc, sd, dd, srcN);
}

// Round 14
// 387.131 us; speedup vs baseline: 1.1668x; 1.1668x over previous
//
#include <hip/hip_runtime.h>

// SoftmaxMatcher on MI355X — round 14.
// = R12 (best: 408us) minus per-phase overhead:
//  * ring-4 x 32KB full units (128KB LDS), ONE barrier per phase. Stage is
//    issued AFTER the barrier into buf (ph+2)%4 — safe: all waves at
//    barrier ph => all finished compute ph-2 (that buffer's last readers).
//    Halves barrier count (MODE0 32->16, MODE1 64->32 per block).
//  * MODE0: S/Su/Sv carried in REGISTERS across all 16 tiles
//    (u = mloc + 128*(mtv&1), v = mtv>>1 are per-phase constants),
//    shuffle-reduced once per block -> per-phase epilogue is 32x{exp2,add,fma};
//    part shrinks to 2MB.
//  * s_setprio around MFMA clusters.
// FIFO waits (per-wave vmcnt, enumerated): MODE0 steady 4, last 0.
// MODE1: ph0,1: 4 | steady 12 | ph31: 8 — osm stores never forced.

typedef short  v8s __attribute__((ext_vector_type(8)));
typedef unsigned short v8u __attribute__((ext_vector_type(8)));
typedef float  v4f __attribute__((ext_vector_type(4)));

#define EXP2_SCALE 144.269504088896f   // 1/(0.01*ln2)
#define WAITV(N) asm volatile("s_waitcnt vmcnt(" #N ")" ::: "memory")
#define SBAR()   __builtin_amdgcn_s_barrier()
#define SCHED()  __builtin_amdgcn_sched_barrier(0)
#define PRIO(N)  __builtin_amdgcn_s_setprio(N)

// ---- workspace layout (bytes) ----
static const size_t O_AHI  = 0;                        // ushort[2048*128]
static const size_t O_ALO  = O_AHI  + 262144ull*2;
static const size_t O_SRCN = O_ALO  + 262144ull*2;     // float[2048*128]
static const size_t O_BHI  = O_SRCN + 262144ull*4;     // ushort[262144*128] 64MB
static const size_t O_BLO  = O_BHI  + 33554432ull*2;   // 64MB
static const size_t O_PART = O_BLO  + 33554432ull*2;   // float4[2048*64]    2MB
static const size_t O_ROWS = O_PART + 2048ull*64*16;   // float4[2048]

static __device__ inline unsigned short f2bf(float x) {
    unsigned u = __float_as_uint(x);
    u = u + 0x7FFFu + ((u >> 16) & 1u);   // RNE
    return (unsigned short)(u >> 16);
}
static __device__ inline float bf2f(unsigned short h) {
    return __uint_as_float(((unsigned)h) << 16);
}

__device__ __forceinline__ void gl_lds16(const void* g, void* l) {
    auto gp = (const __attribute__((address_space(1))) unsigned int*)(uintptr_t)g;
    auto lp = (__attribute__((address_space(3))) unsigned int*)(uintptr_t)l;
    __builtin_amdgcn_global_load_lds(gp, lp, 16, 0, 0);
}

// ---------------- prep: normalize src keypoint descs, bf16 hi/lo, [row][k] ----
__global__ void __launch_bounds__(256) k_prep_src(const float* __restrict__ kd,
                                                  float* __restrict__ srcN,
                                                  unsigned short* __restrict__ Ahi,
                                                  unsigned short* __restrict__ Alo) {
    int gw = blockIdx.x * 4 + (threadIdx.x >> 6);  // 0..2047 = b*512+n
    int l  = threadIdx.x & 63;
    int b  = gw >> 9, n = gw & 511;
    const float* base = kd + (size_t)(2 * b) * 128 * 512;
    float x0 = base[l * 512 + n];
    float x1 = base[(l + 64) * 512 + n];
    float ss = x0 * x0 + x1 * x1;
#pragma unroll
    for (int m = 1; m < 64; m <<= 1) ss += __shfl_xor(ss, m, 64);
    float inv = 1.0f / fmaxf(sqrtf(ss), 1e-12f);
    float xn0 = x0 * inv, xn1 = x1 * inv;
    int ob = gw * 128;
    srcN[ob + l] = xn0;  srcN[ob + l + 64] = xn1;
    unsigned short h0 = f2bf(xn0), h1 = f2bf(xn1);
    Ahi[ob + l] = h0;        Ahi[ob + l + 64] = h1;
    Alo[ob + l] = f2bf(xn0 - bf2f(h0));
    Alo[ob + l + 64] = f2bf(xn1 - bf2f(h1));
}

// ---------------- prep: normalize tgt dense descs -> [m][k] hi/lo -------------
__global__ void __launch_bounds__(256) k_prep_tgt(const float* __restrict__ dd,
                                                  unsigned short* __restrict__ Bhi,
                                                  unsigned short* __restrict__ Blo) {
    int t = blockIdx.x * 128 + (threadIdx.x >> 1);   // 0..262143 = b*65536+p
    int h = threadIdx.x & 1;
    int b = t >> 16;
    int p = t & 65535;
    const float* src = dd + (size_t)(2 * b + 1) * 128 * 65536 + (size_t)(h * 64) * 65536 + p;
    float v[64];
    float ss = 0.f;
#pragma unroll
    for (int c = 0; c < 64; ++c) { float x = src[(size_t)c * 65536]; v[c] = x; ss += x * x; }
    ss += __shfl_xor(ss, 1, 64);
    float inv = 1.0f / fmaxf(sqrtf(ss), 1e-12f);
    size_t ob = (size_t)t * 128 + h * 64;
#pragma unroll
    for (int c8 = 0; c8 < 8; ++c8) {
        v8u h8, l8;
#pragma unroll
        for (int j = 0; j < 8; ++j) {
            float xn = v[c8 * 8 + j] * inv;
            unsigned short hh = f2bf(xn);
            h8[j] = hh;
            l8[j] = f2bf(xn - bf2f(hh));
        }
        *(v8u*)(Bhi + ob + c8 * 8) = h8;
        *(v8u*)(Blo + ob + c8 * 8) = l8;
    }
}

// ---------------- fused GEMM: ring-4, 1 barrier/phase, 16 tiles/block --------
// grid (32 mtg, 4 ny, 4 b) = 512 blocks, 512 thr = 8 waves.
// wave: wm = w>>2 (64-px m-strip), wn = w&3 (32-kp strip).
// MODE 0: 2-term; register-carried {S,U,V}; one float4 store per block.
// MODE 1: 3-term; p = e*invS -> osm (direct v4f stores); sample tail.
template <int MODE>
__global__ void __launch_bounds__(512, 2) k_gemm(const unsigned short* __restrict__ Ahi,
                                                 const unsigned short* __restrict__ Alo,
                                                 const unsigned short* __restrict__ Bhi,
                                                 const unsigned short* __restrict__ Blo,
                                                 const float4* __restrict__ rows,
                                                 float* __restrict__ part,
                                                 float* __restrict__ out,
                                                 const float* __restrict__ ksc,
                                                 const float* __restrict__ sd,
                                                 const float* __restrict__ dd,
                                                 const float* __restrict__ srcN) {
    __shared__ v4f bstage4[8192];          // 128 KB: 4 x 32KB ring
    char* bstage = (char*)bstage4;

    const int tid = threadIdx.x;
    const int l = tid & 63, w = tid >> 6;
    const int wm = w >> 2, wn = w & 3;
    const int l15 = l & 15, l16 = l >> 4;
    const int mtg = blockIdx.x, ny = blockIdx.y, b = blockIdx.z;
    const int mt0 = mtg * 16;
    float* osm = out + 6144;

    // ---- A fragments in VGPRs: [nf 2][ksl 4], hi + lo (64 VGPR) ----
    v8s ahi[2][4], alo[2][4];
    {
        const size_t ar = ((size_t)(b * 512 + ny * 128 + wn * 32 + l15)) * 128 + l16 * 8;
#pragma unroll
        for (int nf = 0; nf < 2; ++nf)
#pragma unroll
            for (int ksl = 0; ksl < 4; ++ksl) {
                ahi[nf][ksl] = *(const v8s*)(Ahi + ar + nf * 2048 + ksl * 32);
                alo[nf][ksl] = *(const v8s*)(Alo + ar + nf * 2048 + ksl * 32);
            }
    }
    float invs[2];
    if (MODE == 1) {
#pragma unroll
        for (int nf = 0; nf < 2; ++nf)
            invs[nf] = rows[b * 512 + ny * 128 + wn * 32 + nf * 16 + l15].x;
    }
    WAITV(0);                               // A regs ready; clean per-wave FIFO

    const size_t pxbase = ((size_t)b * 65536 + (size_t)mt0 * 128) * 128;

#define STAGEU(SRC, eoff, bufidx)                                                   \
    {                                                                               \
        const unsigned short* src_ = (SRC) + pxbase + (eoff);                       \
        char* dst_ = bstage + (bufidx) * 32768;                                     \
        _Pragma("unroll")                                                           \
        for (int i = 0; i < 4; ++i) {                                               \
            int sl = tid + i * 512;                                                 \
            int rl = sl >> 4, gg = sl & 15;                                         \
            gl_lds16(src_ + rl * 128 + ((gg ^ (rl & 15)) << 3), dst_ + (sl << 4));  \
        }                                                                           \
    }
#define PXF(bufbase, mf_, ksl_)                                                     \
    (*(const v8s*)((bufbase) + (wm * 64 + (mf_) * 16 + l15) * 256 +                 \
                   ((((ksl_) * 4 + l16) ^ ((wm * 64 + (mf_) * 16 + l15) & 15)) << 4)))

    v4f acc[4][2];

    if (MODE == 0) {
        float sS[2] = {0.f, 0.f}, sU[2] = {0.f, 0.f}, sV[2] = {0.f, 0.f};
        STAGEU(Bhi, 0, 0);                         // U0
        STAGEU(Bhi, 16384, 1);                     // U1
        // FIFO at WAITV of phase mt: younger-than-U_mt = U_{mt+1}(4) only
        // (U_{mt+2} is staged after this wait; no global stores in MODE0).
        // mt=15: nothing younger -> WAITV(0).
#pragma unroll 1
        for (int mt = 0; mt < 16; ++mt) {
            if (mt == 15) WAITV(0); else WAITV(4);
            SBAR(); SCHED();
            if (mt < 14) STAGEU(Bhi, (size_t)(mt + 2) * 16384, (mt + 2) & 3);
            const char* bb = bstage + (mt & 3) * 32768;
#pragma unroll
            for (int mf = 0; mf < 4; ++mf)
#pragma unroll
                for (int nf = 0; nf < 2; ++nf) { v4f z = {0.f,0.f,0.f,0.f}; acc[mf][nf] = z; }
            PRIO(1);
#pragma unroll
            for (int ksl = 0; ksl < 4; ++ksl) {
                v8s pxf[4];
#pragma unroll
                for (int mf = 0; mf < 4; ++mf) pxf[mf] = PXF(bb, mf, ksl);
#pragma unroll
                for (int mf = 0; mf < 4; ++mf)
#pragma unroll
                    for (int nf = 0; nf < 2; ++nf) {
                        acc[mf][nf] = __builtin_amdgcn_mfma_f32_16x16x32_bf16(pxf[mf], ahi[nf][ksl], acc[mf][nf], 0, 0, 0);
                        acc[mf][nf] = __builtin_amdgcn_mfma_f32_16x16x32_bf16(pxf[mf], alo[nf][ksl], acc[mf][nf], 0, 0, 0);
                    }
            }
            PRIO(0);
            SCHED();
            // register epilogue: ts = tile sum; u = mloc + 128*(mtv&1); v = mtv>>1
            const int mtv = mt0 + mt;
            float ts[2] = {0.f, 0.f};
#pragma unroll
            for (int mf = 0; mf < 4; ++mf) {
                int mloc = wm * 64 + mf * 16 + l16 * 4;
#pragma unroll
                for (int nf = 0; nf < 2; ++nf)
#pragma unroll
                    for (int r = 0; r < 4; ++r) {
                        float e = __builtin_amdgcn_exp2f(fmaf(acc[mf][nf][r], EXP2_SCALE, -EXP2_SCALE));
                        ts[nf] += e;
                        sU[nf] = fmaf(e, (float)(mloc + r), sU[nf]);
                    }
            }
#pragma unroll
            for (int nf = 0; nf < 2; ++nf) {
                sS[nf] += ts[nf];
                sV[nf] = fmaf(ts[nf], (float)(mtv >> 1), sV[nf]);
                if (mtv & 1) sU[nf] = fmaf(ts[nf], 128.f, sU[nf]);
            }
        }
        // once-per-block reduce across l16 groups + store
#pragma unroll
        for (int nf = 0; nf < 2; ++nf) {
            sS[nf] += __shfl_xor(sS[nf], 16, 64); sS[nf] += __shfl_xor(sS[nf], 32, 64);
            sU[nf] += __shfl_xor(sU[nf], 16, 64); sU[nf] += __shfl_xor(sU[nf], 32, 64);
            sV[nf] += __shfl_xor(sV[nf], 16, 64); sV[nf] += __shfl_xor(sV[nf], 32, 64);
        }
        if (l < 16) {
#pragma unroll
            for (int nf = 0; nf < 2; ++nf) {
                int row = b * 512 + ny * 128 + wn * 32 + nf * 16 + l15;
                ((float4*)part)[((size_t)row * 32 + mtg) * 2 + wm]
                    = make_float4(sS[nf], sU[nf], sV[nf], 0.f);
            }
        }
    } else {
        // V_k: k even = Bhi tile k/2 (2-term), k odd = Blo tile k/2 (1-term + 8 stores)
        STAGEU(Bhi, 0, 0);                         // V0
        STAGEU(Blo, 0, 1);                         // V1
        // FIFO at WAITV of phase ph (stage of V_{ph+2} comes AFTER the wait):
        //  ph=0: [V1] -> 4 ; ph=1: [V2] -> 4
        //  steady even: V_{ph+1}(4)+st_{ph-1}(8) = 12
        //  steady odd:  st_{ph-2}(8)+V_{ph+1}(4) = 12
        //  ph=31: st29(8) -> 8
#pragma unroll 1
        for (int ph = 0; ph < 32; ++ph) {
            if (ph <= 1) WAITV(4);
            else if (ph == 31) WAITV(8);
            else WAITV(12);
            SBAR(); SCHED();
            if (ph < 30) {
                const int pn = ph + 2;
                const size_t eoff = (size_t)(pn >> 1) * 16384;
                if ((pn & 1) == 0) STAGEU(Bhi, eoff, pn & 3)
                else               STAGEU(Blo, eoff, pn & 3)
            }
            const char* bb = bstage + (ph & 3) * 32768;
            const int sub = ph & 1;
            if (sub == 0) {
#pragma unroll
                for (int mf = 0; mf < 4; ++mf)
#pragma unroll
                    for (int nf = 0; nf < 2; ++nf) { v4f z = {0.f,0.f,0.f,0.f}; acc[mf][nf] = z; }
            }
            PRIO(1);
#pragma unroll
            for (int ksl = 0; ksl < 4; ++ksl) {
                v8s pxf[4];
#pragma unroll
                for (int mf = 0; mf < 4; ++mf) pxf[mf] = PXF(bb, mf, ksl);
#pragma unroll
                for (int mf = 0; mf < 4; ++mf)
#pragma unroll
                    for (int nf = 0; nf < 2; ++nf) {
                        acc[mf][nf] = __builtin_amdgcn_mfma_f32_16x16x32_bf16(pxf[mf], ahi[nf][ksl], acc[mf][nf], 0, 0, 0);
                        if (sub == 0)
                            acc[mf][nf] = __builtin_amdgcn_mfma_f32_16x16x32_bf16(pxf[mf], alo[nf][ksl], acc[mf][nf], 0, 0, 0);
                    }
            }
            PRIO(0);
            SCHED();
            if (sub == 1) {
                // tile epilogue: direct p stores (8 v4f per thread, along m)
                int mt = ph >> 1;
                size_t mg0 = (size_t)(mt0 + mt) * 128 + wm * 64 + l16 * 4;
#pragma unroll
                for (int mf = 0; mf < 4; ++mf)
#pragma unroll
                    for (int nf = 0; nf < 2; ++nf) {
                        v4f pv;
#pragma unroll
                        for (int r = 0; r < 4; ++r)
                            pv[r] = __builtin_amdgcn_exp2f(fmaf(acc[mf][nf][r], EXP2_SCALE, -EXP2_SCALE)) * invs[nf];
                        size_t ng = (size_t)(b * 512 + ny * 128 + wn * 32 + nf * 16 + l15);
                        __builtin_nontemporal_store(pv, (v4f*)(osm + ng * 65536 + mg0 + mf * 16));
                    }
            }
        }

        // ---- sample tail: 1 row per wave for waves 0..3 (512 blocks x 4) ----
        if (w < 4) {
            const int bidx = mtg + 32 * ny + 128 * b;     // 0..511
            const int r = bidx * 4 + w;                   // 0..2047
            const int rb = r >> 9;
            float4 rs = rows[r];
            float u = rs.y, v = rs.z;
            float un = 2.0f * u / 255.0f - 1.0f;
            float vn = 2.0f * v / 255.0f - 1.0f;
            float x = ((un + 1.0f) * 256.0f - 1.0f) * 0.5f;
            float y = ((vn + 1.0f) * 256.0f - 1.0f) * 0.5f;
            float x0f = floorf(x), y0f = floorf(y);
            int x0 = (int)x0f, y0 = (int)y0f;
            int x1 = x0 + 1, y1 = y0 + 1;
            float wx1 = x - x0f, wy1 = y - y0f;
            float wx0 = 1.0f - wx1, wy0 = 1.0f - wy1;
            float m00 = ((x0 >= 0) & (x0 <= 255) & (y0 >= 0) & (y0 <= 255)) ? 1.f : 0.f;
            float m10 = ((x1 >= 0) & (x1 <= 255) & (y0 >= 0) & (y0 <= 255)) ? 1.f : 0.f;
            float m01 = ((x0 >= 0) & (x0 <= 255) & (y1 >= 0) & (y1 <= 255)) ? 1.f : 0.f;
            float m11 = ((x1 >= 0) & (x1 <= 255) & (y1 >= 0) & (y1 <= 255)) ? 1.f : 0.f;
            int cx0 = min(max(x0, 0), 255), cx1 = min(max(x1, 0), 255);
            int cy0 = min(max(y0, 0), 255), cy1 = min(max(y1, 0), 255);
            int i00 = cy0 * 256 + cx0, i10 = cy0 * 256 + cx1;
            int i01 = cy1 * 256 + cx0, i11 = cy1 * 256 + cx1;
            float w00 = wx0 * wy0 * m00, w10 = wx1 * wy0 * m10;
            float w01 = wx0 * wy1 * m01, w11 = wx1 * wy1 * m11;

            const float* sdb = sd + (size_t)(2 * rb + 1) * 65536;
            float ps = w00 * sdb[i00] + w10 * sdb[i10] + w01 * sdb[i01] + w11 * sdb[i11];

            const float* ddb = dd + (size_t)(2 * rb + 1) * 128 * 65536;
            float dot = 0.f;
#pragma unroll
            for (int h2 = 0; h2 < 2; ++h2) {
                int c = l + h2 * 64;
                const float* dc = ddb + (size_t)c * 65536;
                float pd = w00 * dc[i00] + w10 * dc[i10] + w01 * dc[i01] + w11 * dc[i11];
                dot += srcN[r * 128 + c] * pd;
            }
#pragma unroll
            for (int m = 1; m < 64; m <<= 1) dot += __shfl_xor(dot, m, 64);
            if (l == 0) {
                float dms = dot / 128.0f;
                float sscore = ksc[(2 * rb) * 512 + (r & 511)];
                out[4096 + r] = 0.5f * (dms + 1.0f) * sscore * ps;
            }
        }
    }
#undef STAGEU
#undef PXF
}

// ---------------- reduce partials -> rowstats{invS,u,v}; write pseudo_coords ----
// part: [row 2048][mtg 32][wm 2] float4{S,U,V,0} -> 64 float4 per row
__global__ void __launch_bounds__(256) k_reduce(const float4* __restrict__ part,
                                                float4* __restrict__ rows,
                                                float* __restrict__ out) {
    int r = blockIdx.x * 4 + (threadIdx.x >> 6);  // 0..2047
    int l = threadIdx.x & 63;
    float4 pp = part[(size_t)r * 64 + l];
    float S = pp.x, Su = pp.y, Sv = pp.z;
#pragma unroll
    for (int m = 1; m < 64; m <<= 1) {
        S += __shfl_xor(S, m, 64);
        Su += __shfl_xor(Su, m, 64);
        Sv += __shfl_xor(Sv, m, 64);
    }
    if (l == 0) {
        float invS = 1.0f / S;
        float u = Su * invS, v = Sv * invS;
        rows[r] = make_float4(invS, u, v, 0.f);
        out[r * 2] = u;
        out[r * 2 + 1] = v;
    }
}

extern "C" void kernel_launch(void* const* d_in, const int* in_sizes, int n_in,
                              void* d_out, int out_size, void* d_ws, size_t ws_size,
                              hipStream_t stream) {
    const float* ksc = (const float*)d_in[0];  // (8,1,512)
    const float* kd  = (const float*)d_in[1];  // (8,128,512)
    const float* sd  = (const float*)d_in[2];  // (8,1,256,256)
    const float* dd  = (const float*)d_in[3];  // (8,128,256,256)
    float* out = (float*)d_out;                // coords(4096) | mw(2048) | sm(134217728)
    char* ws = (char*)d_ws;

    unsigned short* Ahi  = (unsigned short*)(ws + O_AHI);
    unsigned short* Alo  = (unsigned short*)(ws + O_ALO);
    float*          srcN = (float*)(ws + O_SRCN);
    unsigned short* Bhi  = (unsigned short*)(ws + O_BHI);
    unsigned short* Blo  = (unsigned short*)(ws + O_BLO);
    float*          part = (float*)(ws + O_PART);
    float4*         rows = (float4*)(ws + O_ROWS);

    k_prep_src<<<512, 256, 0, stream>>>(kd, srcN, Ahi, Alo);
    k_prep_tgt<<<2048, 256, 0, stream>>>(dd, Bhi, Blo);
    k_gemm<0><<<dim3(32, 4, 4), 512, 0, stream>>>(Ahi, Alo, Bhi, Blo, rows, part, out, ksc, sd, dd, srcN);
    k_reduce<<<512, 256, 0, stream>>>((const float4*)part, rows, out);
    k_gemm<1><<<dim3(32, 4, 4), 512, 0, stream>>>(Ahi, Alo, Bhi, Blo, rows, part, out, ksc, sd, dd, srcN);
}